// Round 7
// baseline (437.635 us; speedup 1.0000x reference)
//
#include <hip/hip_runtime.h>
#include <hip/hip_bf16.h>

#define BB 4
#define CC 128
#define NN 4096
#define KK 16
#define FLT_BIG 3.402823466e+38f

typedef __attribute__((ext_vector_type(8))) short short8v;
typedef __attribute__((ext_vector_type(4))) short short4v;
typedef __attribute__((ext_vector_type(4))) float f32x4;

__device__ __forceinline__ unsigned short f2b(float x) {   // RNE f32->bf16 (manual)
  union { float f; unsigned u; } v; v.f = x;
  unsigned r = v.u + 0x7fffu + ((v.u >> 16) & 1u);
  return (unsigned short)(r >> 16);
}
__device__ __forceinline__ float b2f(unsigned short h) {
  union { float f; unsigned u; } v; v.u = ((unsigned)h) << 16; return v.f;
}
// packed RNE pair: [15:0]=bf16(a), [31:16]=bf16(b)  (v_cvt_pk_bf16_f32)
__device__ __forceinline__ unsigned pkrn(float a, float b) {
  __hip_bfloat162 t = __float22bfloat162_rn(make_float2(a, b));
  union { __hip_bfloat162 h; unsigned u; } c; c.h = t; return c.u;
}
// split (a,b) into packed hi + packed lo bf16 pairs
__device__ __forceinline__ void split2(float a, float b, unsigned& h, unsigned& l) {
  h = pkrn(a, b);
  union { unsigned u; float f; } lo, hi2;
  lo.u = h << 16;
  hi2.u = h & 0xffff0000u;
  l = pkrn(a - lo.f, b - hi2.f);
}

// ---- shared distance: identical instruction sequence everywhere (bit-exact re-eval) ----
__device__ __forceinline__ float dist4(const float4 q, const float4 c) {
  float t = __fmaf_rn(q.x, c.x, __fmaf_rn(q.y, c.y, __fmul_rn(q.z, c.z)));
  return __fmaf_rn(-2.f, t, q.w + c.w);
}

// ================= setup: prep(pkg) + wprep(weight frags) + xpose(xin planes) =============
__global__ __launch_bounds__(256) void setup_kernel(
    const float* __restrict__ p, const float* __restrict__ x,
    const float* __restrict__ d2W, const float* __restrict__ g1W,
    const float* __restrict__ g2W, const float* __restrict__ topW,
    const float* __restrict__ phiW, const float* __restrict__ psiW,
    const float* __restrict__ alpW, const float* __restrict__ dnW,
    float4* __restrict__ pkg, unsigned short* __restrict__ wpk,
    unsigned short* __restrict__ xh, unsigned short* __restrict__ xl)
{
  __shared__ float t[64][65];
  const int bid = blockIdx.x, tid = threadIdx.x;
  if (bid < 64) {            // ---- prep ----
    int i = bid * 256 + tid;
    int b = i >> 12, m = i & (NN - 1);
    const float* pb = p + (size_t)b * 3 * NN;
    float xx = pb[m], yy = pb[NN + m], zz = pb[2 * NN + m];
    pkg[i] = make_float4(xx, yy, zz, __fmaf_rn(xx, xx, __fmaf_rn(yy, yy, __fmul_rn(zz, zz))));
  } else if (bid < 128) {    // ---- wprep: mats 0=d2 1=g1 2=g2 3=top 4=phi 5=psi 6=alpha 7=down
    int tt = (bid - 64) * 256 + tid;       // 0..16383
    int mat = tt >> 11, r = tt & 2047;
    int ct = r >> 8, ks = (r >> 6) & 3, lane = r & 63;
    const float* W;
    switch (mat) {
      case 0: W = d2W; break;  case 1: W = g1W; break;
      case 2: W = g2W; break;  case 3: W = topW; break;
      case 4: W = phiW; break; case 5: W = psiW; break;
      case 6: W = alpW; break; default: W = dnW; break;
    }
    int row = ct * 16 + (lane & 15);
    int k0 = ks * 32 + (lane >> 4) * 8;
    const float* src = &W[row * 128 + k0];
    unsigned short* dh = &wpk[((size_t)(((mat * 2 + 0) * 8 + ct) * 4 + ks) * 64 + lane) * 8];
    unsigned short* dl = &wpk[((size_t)(((mat * 2 + 1) * 8 + ct) * 4 + ks) * 64 + lane) * 8];
#pragma unroll
    for (int e = 0; e < 8; ++e) {
      float v = src[e];
      unsigned short h = f2b(v);
      dh[e] = h;
      dl[e] = f2b(v - b2f(h));
    }
  } else {                   // ---- xpose: input_x [B][C][N] -> hi/lo planes [B][N][C]
    int bid2 = bid - 128;
    int nb = bid2 & 63, cb = (bid2 >> 6) & 1, b = bid2 >> 7;
    const int c0 = cb * 64, n0 = nb * 64;
    const int tn = tid & 63, tq = tid >> 6;
    const float* xb = x + ((size_t)b * CC + c0) * NN + n0;
#pragma unroll
    for (int i = 0; i < 16; ++i) {
      int c = tq * 16 + i;
      t[c][tn] = xb[(size_t)c * NN + tn];
    }
    __syncthreads();
#pragma unroll
    for (int i = 0; i < 16; ++i) {
      int nl = tq * 16 + i;
      float v = t[tn][nl];
      unsigned short h = f2b(v);
      size_t o = ((size_t)b * NN + n0 + nl) * CC + c0 + tn;
      xh[o] = h;
      xl[o] = f2b(v - b2f(h));
    }
  }
}

// ================= KNN: exact 16-NN set (order-free; boundary ties -> lowest index) ======
__global__ __launch_bounds__(512, 2) void knn_kernel(const float4* __restrict__ pkg,
                                                     int* __restrict__ outidx)
{
  __shared__ float BD[8][64][17];
  __shared__ float TS[64];
  __shared__ int   CNT[64];
  __shared__ float COLd[64][20];
  __shared__ int   COLi[64][20];
  const int b = blockIdx.y;
  const int tid = threadIdx.x;
  const int lane = tid & 63;
  const int w = tid >> 6;
  const int n = blockIdx.x * 64 + lane;
  const float4* PB = pkg + (size_t)b * NN;
  const float4 qc = PB[n];
  if (tid < 64) CNT[tid] = 0;

  float bd[16];
#pragma unroll
  for (int t = 0; t < 16; ++t) bd[t] = FLT_BIG;
  const int m0 = w * 512;
#pragma unroll 2
  for (int m = m0; m < m0 + 512; ++m) {
    float4 c = PB[m];
    float d = dist4(qc, c);
    if (d < bd[15]) {   // whole-wave skip when no lane inserts (identical semantics)
#pragma unroll
      for (int t = 15; t >= 1; --t) bd[t] = __builtin_amdgcn_fmed3f(bd[t - 1], d, bd[t]);
      bd[0] = fminf(bd[0], d);
    }
  }
#pragma unroll
  for (int t = 0; t < 16; ++t) BD[w][lane][t] = bd[t];
  __syncthreads();

  if (tid < 64) {
    const int q = tid;
    int h0 = 0, h1 = 0, h2 = 0, h3 = 0, h4 = 0, h5 = 0, h6 = 0, h7 = 0;
    float mv = FLT_BIG;
#pragma unroll 1
    for (int r = 0; r < 16; ++r) {
      float v0 = BD[0][q][h0], v1 = BD[1][q][h1], v2 = BD[2][q][h2], v3 = BD[3][q][h3];
      float v4 = BD[4][q][h4], v5 = BD[5][q][h5], v6 = BD[6][q][h6], v7 = BD[7][q][h7];
      mv = v0; int mw = 0;
      if (v1 < mv) { mv = v1; mw = 1; }
      if (v2 < mv) { mv = v2; mw = 2; }
      if (v3 < mv) { mv = v3; mw = 3; }
      if (v4 < mv) { mv = v4; mw = 4; }
      if (v5 < mv) { mv = v5; mw = 5; }
      if (v6 < mv) { mv = v6; mw = 6; }
      if (v7 < mv) { mv = v7; mw = 7; }
      h0 += (mw == 0); h1 += (mw == 1); h2 += (mw == 2); h3 += (mw == 3);
      h4 += (mw == 4); h5 += (mw == 5); h6 += (mw == 6); h7 += (mw == 7);
    }
    TS[q] = mv;
  }
  __syncthreads();

  {
    const float thr = TS[lane];
#pragma unroll 4
    for (int m = m0; m < m0 + 512; ++m) {
      float4 c = PB[m];
      float d = dist4(qc, c);
      if (d <= thr) {
        int pos = atomicAdd(&CNT[lane], 1);
        if (pos < 20) { COLd[lane][pos] = d; COLi[lane][pos] = m; }
      }
    }
  }
  __syncthreads();

  if (tid < 64) {
    const int q = tid;
    int c = CNT[q]; if (c > 20) c = 20;
    int* op = outidx + ((size_t)b * NN + blockIdx.x * 64 + q) * KK;
    if (c == KK) {
#pragma unroll
      for (int o = 0; o < KK; ++o) op[o] = COLi[q][o];
    } else {
      const float T = TS[q];
      int less = 0;
      for (int s = 0; s < c; ++s) less += (COLd[q][s] < T);
      int need = KK - less;
      int o = 0;
      for (int s = 0; s < c; ++s)
        if (COLd[q][s] < T) op[o++] = COLi[q][s];
      for (int s = 0; s < c; ++s) {
        if (COLd[q][s] == T) {
          int idx = COLi[q][s];
          int rank = 0;
          for (int s2 = 0; s2 < c; ++s2)
            rank += (COLd[q][s2] == T && COLi[q][s2] < idx);
          if (rank < need) op[o++] = idx;
        }
      }
    }
  }
}

// ================= feat: x = top(xin) in LDS; then phi/psi (f32) + alpha (bf16) ==========
__global__ __launch_bounds__(256) void feat_kernel(
    const unsigned short* __restrict__ xh, const unsigned short* __restrict__ xl,
    const unsigned short* __restrict__ wpk,
    const float* __restrict__ topb, const float* __restrict__ phib,
    const float* __restrict__ psib, const float* __restrict__ alpb,
    float* __restrict__ phit, float* __restrict__ psit,
    unsigned short* __restrict__ alpt)
{
  __shared__ float xtile[32][129];
  const int b = blockIdx.y, n0 = blockIdx.x * 32;
  const int tid = threadIdx.x, l = tid & 63, w = tid >> 6;
  const int lr = l & 15, lh = l >> 4;
  const int nt = w & 1, cq = w >> 1;
  // ---- phase 1: x rows (nt half) into LDS ----
  {
    const int nrow = n0 + nt * 16 + lr;
    const unsigned short* xhp = xh + ((size_t)b * NN + nrow) * CC;
    const unsigned short* xlp = xl + ((size_t)b * NN + nrow) * CC;
    short8v Ah[4], Al[4];
#pragma unroll
    for (int ks = 0; ks < 4; ++ks) {
      Ah[ks] = *(const short8v*)&xhp[ks * 32 + lh * 8];
      Al[ks] = *(const short8v*)&xlp[ks * 32 + lh * 8];
    }
    const int nDl = nt * 16 + lh * 4;
#pragma unroll
    for (int cc = 0; cc < 4; ++cc) {
      const int colt = cq * 4 + cc;
      f32x4 acc = (f32x4){0.f, 0.f, 0.f, 0.f};
#pragma unroll
      for (int ks = 0; ks < 4; ++ks) {
        short8v Wh = *(const short8v*)&wpk[((size_t)(((3 * 2 + 0) * 8 + colt) * 4 + ks) * 64 + l) * 8];
        short8v Wl = *(const short8v*)&wpk[((size_t)(((3 * 2 + 1) * 8 + colt) * 4 + ks) * 64 + l) * 8];
        acc = __builtin_amdgcn_mfma_f32_16x16x32_bf16(Ah[ks], Wh, acc, 0, 0, 0);
        acc = __builtin_amdgcn_mfma_f32_16x16x32_bf16(Al[ks], Wh, acc, 0, 0, 0);
        acc = __builtin_amdgcn_mfma_f32_16x16x32_bf16(Ah[ks], Wl, acc, 0, 0, 0);
      }
      float bv = topb[colt * 16 + lr];
#pragma unroll
      for (int r = 0; r < 4; ++r) xtile[nDl + r][colt * 16 + lr] = acc[r] + bv;
    }
  }
  __syncthreads();
  // ---- phase 2: rebuild pair A-frags from LDS, run phi/psi/alpha ----
  short8v Ah[4], Al[4];
  {
    const int rl = nt * 16 + lr;
#pragma unroll
    for (int ks = 0; ks < 4; ++ks) {
      union { short8v s; unsigned u[4]; } H, L;
#pragma unroll
      for (int i = 0; i < 4; ++i) {
        float a = xtile[rl][ks * 32 + lh * 8 + 2 * i];
        float bb = xtile[rl][ks * 32 + lh * 8 + 2 * i + 1];
        split2(a, bb, H.u[i], L.u[i]);
      }
      Ah[ks] = H.s; Al[ks] = L.s;
    }
  }
  const int nD = n0 + nt * 16 + lh * 4;
#pragma unroll
  for (int m = 0; m < 3; ++m) {
    const int mat = 4 + m;
    const float* bias = (m == 0) ? phib : (m == 1) ? psib : alpb;
#pragma unroll
    for (int cc = 0; cc < 4; ++cc) {
      const int colt = cq * 4 + cc;
      f32x4 acc = (f32x4){0.f, 0.f, 0.f, 0.f};
#pragma unroll
      for (int ks = 0; ks < 4; ++ks) {
        short8v Wh = *(const short8v*)&wpk[((size_t)(((mat * 2 + 0) * 8 + colt) * 4 + ks) * 64 + l) * 8];
        short8v Wl = *(const short8v*)&wpk[((size_t)(((mat * 2 + 1) * 8 + colt) * 4 + ks) * 64 + l) * 8];
        acc = __builtin_amdgcn_mfma_f32_16x16x32_bf16(Ah[ks], Wh, acc, 0, 0, 0);
        acc = __builtin_amdgcn_mfma_f32_16x16x32_bf16(Al[ks], Wh, acc, 0, 0, 0);
        acc = __builtin_amdgcn_mfma_f32_16x16x32_bf16(Ah[ks], Wl, acc, 0, 0, 0);
      }
      float bv = bias[colt * 16 + lr];
      if (m == 2) {
#pragma unroll
        for (int r = 0; r < 4; ++r)
          alpt[((size_t)b * NN + nD + r) * CC + colt * 16 + lr] = f2b(acc[r] + bv);
      } else {
        float* outp = (m == 0) ? phit : psit;
#pragma unroll
        for (int r = 0; r < 4; ++r)
          outp[((size_t)b * NN + nD + r) * CC + colt * 16 + lr] = acc[r] + bv;
      }
    }
  }
}

// ================= down: out = dnW @ y + b + res  (y from pair planes) ==================
__global__ __launch_bounds__(256) void down_kernel(
    const unsigned short* __restrict__ yh, const unsigned short* __restrict__ yl,
    const unsigned short* __restrict__ wpk,
    const float* __restrict__ bias, const float* __restrict__ res,
    float* __restrict__ out)
{
  const int b = blockIdx.y, n0 = blockIdx.x * 64;
  const int tid = threadIdx.x, l = tid & 63, w = tid >> 6;
  const int lr = l & 15, lh = l >> 4;
  short8v Ah[2][4], Al[2][4];
#pragma unroll
  for (int ct = 0; ct < 2; ++ct)
#pragma unroll
    for (int ks = 0; ks < 4; ++ks) {
      Ah[ct][ks] = *(const short8v*)&wpk[((size_t)(((7 * 2 + 0) * 8 + (2 * w + ct)) * 4 + ks) * 64 + l) * 8];
      Al[ct][ks] = *(const short8v*)&wpk[((size_t)(((7 * 2 + 1) * 8 + (2 * w + ct)) * 4 + ks) * 64 + l) * 8];
    }
  f32x4 acc[2][4];
#pragma unroll
  for (int colt = 0; colt < 4; ++colt) {
    const int n = n0 + colt * 16 + lr;
    const unsigned short* yhp = yh + ((size_t)b * NN + n) * CC;
    const unsigned short* ylp = yl + ((size_t)b * NN + n) * CC;
#pragma unroll
    for (int ct = 0; ct < 2; ++ct) acc[ct][colt] = (f32x4){0.f, 0.f, 0.f, 0.f};
#pragma unroll
    for (int ks = 0; ks < 4; ++ks) {
      short8v Bh = *(const short8v*)&yhp[ks * 32 + lh * 8];
      short8v Bl = *(const short8v*)&ylp[ks * 32 + lh * 8];
#pragma unroll
      for (int ct = 0; ct < 2; ++ct) {
        acc[ct][colt] = __builtin_amdgcn_mfma_f32_16x16x32_bf16(Ah[ct][ks], Bh, acc[ct][colt], 0, 0, 0);
        acc[ct][colt] = __builtin_amdgcn_mfma_f32_16x16x32_bf16(Ah[ct][ks], Bl, acc[ct][colt], 0, 0, 0);
        acc[ct][colt] = __builtin_amdgcn_mfma_f32_16x16x32_bf16(Al[ct][ks], Bh, acc[ct][colt], 0, 0, 0);
      }
    }
  }
#pragma unroll
  for (int ct = 0; ct < 2; ++ct) {
    const int c0 = 32 * w + ct * 16 + lh * 4;
#pragma unroll
    for (int r = 0; r < 4; ++r) {
      float bv = bias[c0 + r];
#pragma unroll
      for (int colt = 0; colt < 4; ++colt) {
        size_t o = ((size_t)b * CC + c0 + r) * NN + n0 + colt * 16 + lr;
        out[o] = acc[ct][colt][r] + bv + res[o];
      }
    }
  }
}

// ================= Fused core: act XOR-swizzle, inline gathers, bcast-softmax ============
#define TNP 4
// swizzle: XOR 16-B chunk index (bits 3..5 of halfword idx) with row&7 -> <=2-way banks
#define ASW(row, c) ((c) ^ (((row) & 7) << 3))
__global__ __launch_bounds__(256, 4) void fused_kernel(
    const float* __restrict__ p, const int* __restrict__ idxg,
    const float* __restrict__ phi_t, const float* __restrict__ psi_t,
    const unsigned short* __restrict__ alp_b, const unsigned short* __restrict__ wpk,
    const float* __restrict__ d1W, const float* __restrict__ d1b,
    const float* __restrict__ d2b, const float* __restrict__ g1b,
    const float* __restrict__ g2b,
    unsigned short* __restrict__ yh, unsigned short* __restrict__ yl)
{
  __shared__ __align__(16) unsigned short act[2][64][136];  // [hi/lo][col][c]
  __shared__ int idxs[64];
  const int b = blockIdx.y;
  const int n0 = blockIdx.x * TNP;
  const int tid = threadIdx.x;
  const int l = tid & 63, w = tid >> 6;
  const int lr = l & 15, lh = l >> 4;

  if (tid < 64) idxs[tid] = idxg[((size_t)b * NN + n0 + (tid >> 4)) * KK + (tid & 15)];
  __syncthreads();

  // ---------- stage 0: rel -> pos1 = relu(d1W rel + d1b), hi/lo into act ----------
  {
    const int col = tid & 63, q = tid >> 6;
    const int pt = col >> 4;
    const int j = idxs[col];
    const float* pb = p + (size_t)b * 3 * NN;
    float r0 = pb[n0 + pt] - pb[j];
    float r1 = pb[NN + n0 + pt] - pb[NN + j];
    float r2 = pb[2 * NN + n0 + pt] - pb[2 * NN + j];
#pragma unroll
    for (int ch = 0; ch < 4; ++ch) {
      int c0 = q * 32 + ch * 8;
      float v[8];
#pragma unroll
      for (int e = 0; e < 8; ++e) {
        int c = c0 + e;
        v[e] = fmaxf(d1W[c * 3 + 0] * r0 + d1W[c * 3 + 1] * r1 + d1W[c * 3 + 2] * r2 + d1b[c], 0.f);
      }
      uint4 H, L;
      split2(v[0], v[1], H.x, L.x); split2(v[2], v[3], H.y, L.y);
      split2(v[4], v[5], H.z, L.z); split2(v[6], v[7], H.w, L.w);
      *(uint4*)&act[0][col][ASW(col, c0)] = H;
      *(uint4*)&act[1][col][ASW(col, c0)] = L;
    }
  }
  __syncthreads();

  int idxv[TNP];
#pragma unroll
  for (int colt = 0; colt < TNP; ++colt) idxv[colt] = idxs[colt * 16 + lr];

  f32x4 acc[2][TNP];
  short8v Af[2][4];

#define LOADA(MAT) do {                                                                 \
  _Pragma("unroll") for (int ct = 0; ct < 2; ++ct)                                      \
    _Pragma("unroll") for (int ks = 0; ks < 4; ++ks)                                    \
      Af[ct][ks] = *(const short8v*)&wpk[((size_t)((((MAT) * 2 + 0) * 8 + (2 * w + ct)) * 4 + ks) * 64 + l) * 8]; \
  } while (0)

#define MMUL() do {                                                                     \
  _Pragma("unroll") for (int ct = 0; ct < 2; ++ct)                                      \
    _Pragma("unroll") for (int colt = 0; colt < TNP; ++colt)                            \
      acc[ct][colt] = (f32x4){0.f, 0.f, 0.f, 0.f};                                      \
  _Pragma("unroll") for (int colt = 0; colt < TNP; ++colt) {                            \
    const int row_ = colt * 16 + lr;                                                    \
    short8v Bh[4], Bl[4];                                                               \
    _Pragma("unroll") for (int ks = 0; ks < 4; ++ks) {                                  \
      Bh[ks] = *(const short8v*)&act[0][row_][ASW(row_, ks * 32 + lh * 8)];             \
      Bl[ks] = *(const short8v*)&act[1][row_][ASW(row_, ks * 32 + lh * 8)];             \
    }                                                                                   \
    _Pragma("unroll") for (int ct = 0; ct < 2; ++ct)                                    \
      _Pragma("unroll") for (int ks = 0; ks < 4; ++ks) {                                \
        acc[ct][colt] = __builtin_amdgcn_mfma_f32_16x16x32_bf16(Af[ct][ks], Bh[ks],     \
                                                                acc[ct][colt], 0, 0, 0); \
        acc[ct][colt] = __builtin_amdgcn_mfma_f32_16x16x32_bf16(Af[ct][ks], Bl[ks],     \
                                                                acc[ct][colt], 0, 0, 0); \
      }                                                                                 \
  } } while (0)

  // ---------- d2: pos = d2W @ pos1 + d2b (kept in registers) ----------
  LOADA(0); MMUL();
  float pos[2][TNP][4];
#pragma unroll
  for (int ct = 0; ct < 2; ++ct) {
    f32x4 bv = *(const f32x4*)&d2b[32 * w + ct * 16 + lh * 4];
#pragma unroll
    for (int colt = 0; colt < TNP; ++colt)
#pragma unroll
      for (int r = 0; r < 4; ++r) pos[ct][colt][r] = acc[ct][colt][r] + bv[r];
  }
  __syncthreads();   // all waves done reading pos1

  // ---------- ain = pos + phi[n] - psi[idx] -> act (inline gathers) ----------
#pragma unroll
  for (int colt = 0; colt < TNP; ++colt) {
    size_t prow = ((size_t)b * NN + n0 + colt) * CC;
    size_t srow = ((size_t)b * NN + idxv[colt]) * CC;
#pragma unroll
    for (int ct = 0; ct < 2; ++ct) {
      int c0 = 32 * w + ct * 16 + lh * 4;
      f32x4 ph = *(const f32x4*)&phi_t[prow + c0];
      f32x4 ps = *(const f32x4*)&psi_t[srow + c0];
      float v[4];
#pragma unroll
      for (int r = 0; r < 4; ++r) v[r] = pos[ct][colt][r] + ph[r] - ps[r];
      uint2 H, L;
      split2(v[0], v[1], H.x, L.x); split2(v[2], v[3], H.y, L.y);
      const int row = colt * 16 + lr;
      *(uint2*)&act[0][row][ASW(row, c0)] = H;
      *(uint2*)&act[1][row][ASW(row, c0)] = L;
    }
  }
  __syncthreads();

  // ---------- g1: h = relu(g1W @ ain + g1b) -> act ----------
  LOADA(1); MMUL();
  __syncthreads();   // all waves done reading ain
#pragma unroll
  for (int ct = 0; ct < 2; ++ct) {
    f32x4 bv = *(const f32x4*)&g1b[32 * w + ct * 16 + lh * 4];
    int c0 = 32 * w + ct * 16 + lh * 4;
#pragma unroll
    for (int colt = 0; colt < TNP; ++colt) {
      float v[4];
#pragma unroll
      for (int r = 0; r < 4; ++r) v[r] = fmaxf(acc[ct][colt][r] + bv[r], 0.f);
      uint2 H, L;
      split2(v[0], v[1], H.x, L.x); split2(v[2], v[3], H.y, L.y);
      const int row = colt * 16 + lr;
      *(uint2*)&act[0][row][ASW(row, c0)] = H;
      *(uint2*)&act[1][row][ASW(row, c0)] = L;
    }
  }
  __syncthreads();

  // ---------- g2: attn = g2W @ h + g2b ----------
  LOADA(2); MMUL();
#pragma unroll
  for (int ct = 0; ct < 2; ++ct) {
    f32x4 bv = *(const f32x4*)&g2b[32 * w + ct * 16 + lh * 4];
#pragma unroll
    for (int colt = 0; colt < TNP; ++colt)
#pragma unroll
      for (int r = 0; r < 4; ++r) acc[ct][colt][r] += bv[r];
  }

  // ---------- softmax over k (= lr lanes, group base broadcast; shift-invariant) ----------
#pragma unroll
  for (int ct = 0; ct < 2; ++ct)
#pragma unroll
    for (int colt = 0; colt < TNP; ++colt)
#pragma unroll
      for (int r = 0; r < 4; ++r) {
        float a = acc[ct][colt][r];
        float m = __shfl(a, l & 48);          // group-base value (exact softmax shift)
        float e = __expf(a - m);
        float s = e;
        s += __shfl_xor(s, 1);
        s += __shfl_xor(s, 2);
        s += __shfl_xor(s, 4);
        s += __shfl_xor(s, 8);
        acc[ct][colt][r] = e * __builtin_amdgcn_rcpf(s);
      }

  __syncthreads();   // all waves past their last act read (g2 MMUL) -> safe to reuse act
  unsigned short* yst = &act[0][0][0];   // staging: rows 0..3 = yh[colt], rows 4..7 = yl

  // ---------- combine: y_t[n][c] = sum_k wgt * (alpha[idx] + pos) ----------
#pragma unroll
  for (int colt = 0; colt < TNP; ++colt) {
    size_t arow = ((size_t)b * NN + idxv[colt]) * CC;
#pragma unroll
    for (int ct = 0; ct < 2; ++ct) {
      int c0 = 32 * w + ct * 16 + lh * 4;
      uint2 ua = *(const uint2*)&alp_b[arow + c0];
      union { unsigned u; float f; } a0, a1, a2, a3;
      a0.u = ua.x << 16; a1.u = ua.x & 0xffff0000u;
      a2.u = ua.y << 16; a3.u = ua.y & 0xffff0000u;
      float av[4] = {a0.f, a1.f, a2.f, a3.f};
      float yv[4];
#pragma unroll
      for (int r = 0; r < 4; ++r) {
        float part = acc[ct][colt][r] * (av[r] + pos[ct][colt][r]);
        part += __shfl_xor(part, 1);
        part += __shfl_xor(part, 2);
        part += __shfl_xor(part, 4);
        part += __shfl_xor(part, 8);
        yv[r] = part;
      }
      if (lr == 0) {
        uint2 H, L;
        split2(yv[0], yv[1], H.x, L.x); split2(yv[2], yv[3], H.y, L.y);
        *(uint2*)&yst[(size_t)colt * 128 + c0] = H;
        *(uint2*)&yst[(size_t)(4 + colt) * 128 + c0] = L;
      }
    }
  }
  __syncthreads();
  // ---------- coalesced y writeout: 2 KB, 16B per thread ----------
  if (tid < 128) {
    int plane = tid >> 6, row = (tid >> 4) & 3, chunk = tid & 15;
    uint4 v4 = *(const uint4*)&yst[(size_t)(plane * 4 + row) * 128 + chunk * 8];
    unsigned short* dst = (plane ? yl : yh) + ((size_t)b * NN + n0 + row) * CC + chunk * 8;
    *(uint4*)dst = v4;
  }
#undef LOADA
#undef MMUL
}

// =============================================================================================
extern "C" void kernel_launch(void* const* d_in, const int* in_sizes, int n_in,
                              void* d_out, int out_size, void* d_ws, size_t ws_size,
                              hipStream_t stream) {
  const float* input_p = (const float*)d_in[0];
  const float* input_x = (const float*)d_in[1];
  const float* top_W   = (const float*)d_in[2];  const float* top_b   = (const float*)d_in[3];
  const float* down_W  = (const float*)d_in[4];  const float* down_b  = (const float*)d_in[5];
  const float* phi_W   = (const float*)d_in[6];  const float* phi_b   = (const float*)d_in[7];
  const float* psi_W   = (const float*)d_in[8];  const float* psi_b   = (const float*)d_in[9];
  const float* alpha_W = (const float*)d_in[10]; const float* alpha_b = (const float*)d_in[11];
  const float* g1_W    = (const float*)d_in[12]; const float* g1_b    = (const float*)d_in[13];
  const float* g2_W    = (const float*)d_in[14]; const float* g2_b    = (const float*)d_in[15];
  const float* d1_W    = (const float*)d_in[16]; const float* d1_b    = (const float*)d_in[17];
  const float* d2_W    = (const float*)d_in[18]; const float* d2_b    = (const float*)d_in[19];
  float* out = (float*)d_out;

  char* ws = (char*)d_ws;
  int*            ws_idx   = (int*)ws;                                         // 1 MB
  unsigned short* ws_xin_h = (unsigned short*)(ws + (size_t)1  * (1 << 20));   // 4 MB (reused as y_h)
  unsigned short* ws_xin_l = (unsigned short*)(ws + (size_t)5  * (1 << 20));   // 4 MB (reused as y_l)
  float*          ws_phi   = (float*)(ws + (size_t)9  * (1 << 20));            // 8 MB
  float*          ws_psi   = (float*)(ws + (size_t)17 * (1 << 20));            // 8 MB
  unsigned short* ws_alp   = (unsigned short*)(ws + (size_t)25 * (1 << 20));   // 4 MB (bf16)
  float4*         ws_pkg   = (float4*)(ws + (size_t)29 * (1 << 20));           // 256 KB
  unsigned short* ws_wpk   = (unsigned short*)(ws + (size_t)29 * (1 << 20) + (1 << 18)); // 512 KB
  unsigned short* ws_y_h = ws_xin_h;   // xin consumed by feat; stream-ordered reuse
  unsigned short* ws_y_l = ws_xin_l;

  setup_kernel<<<640, 256, 0, stream>>>(input_p, input_x, d2_W, g1_W, g2_W, top_W,
                                        phi_W, psi_W, alpha_W, down_W,
                                        ws_pkg, ws_wpk, ws_xin_h, ws_xin_l);
  knn_kernel<<<dim3(NN / 64, BB), 512, 0, stream>>>(ws_pkg, ws_idx);
  feat_kernel<<<dim3(NN / 32, BB), 256, 0, stream>>>(ws_xin_h, ws_xin_l, ws_wpk,
                                                     top_b, phi_b, psi_b, alpha_b,
                                                     ws_phi, ws_psi, ws_alp);
  fused_kernel<<<dim3(NN / TNP, BB), 256, 0, stream>>>(input_p, ws_idx, ws_phi, ws_psi, ws_alp,
                                                       ws_wpk, d1_W, d1_b, d2_b, g1_b, g2_b,
                                                       ws_y_h, ws_y_l);
  down_kernel<<<dim3(NN / 64, BB), 256, 0, stream>>>(ws_y_h, ws_y_l, ws_wpk, down_b,
                                                     input_x, out);
}

// Round 9
// 368.898 us; speedup vs baseline: 1.1863x; 1.1863x over previous
//
#include <hip/hip_runtime.h>
#include <hip/hip_bf16.h>

#define BB 4
#define CC 128
#define NN 4096
#define KK 16
#define FLT_BIG 3.402823466e+38f

typedef __attribute__((ext_vector_type(8))) short short8v;
typedef __attribute__((ext_vector_type(4))) short short4v;
typedef __attribute__((ext_vector_type(4))) float f32x4;

__device__ __forceinline__ unsigned short f2b(float x) {   // RNE f32->bf16 (manual)
  union { float f; unsigned u; } v; v.f = x;
  unsigned r = v.u + 0x7fffu + ((v.u >> 16) & 1u);
  return (unsigned short)(r >> 16);
}
__device__ __forceinline__ float b2f(unsigned short h) {
  union { float f; unsigned u; } v; v.u = ((unsigned)h) << 16; return v.f;
}
// packed RNE pair: [15:0]=bf16(a), [31:16]=bf16(b)  (v_cvt_pk_bf16_f32)
__device__ __forceinline__ unsigned pkrn(float a, float b) {
  __hip_bfloat162 t = __float22bfloat162_rn(make_float2(a, b));
  union { __hip_bfloat162 h; unsigned u; } c; c.h = t; return c.u;
}
// split (a,b) into packed hi + packed lo bf16 pairs
__device__ __forceinline__ void split2(float a, float b, unsigned& h, unsigned& l) {
  h = pkrn(a, b);
  union { unsigned u; float f; } lo, hi2;
  lo.u = h << 16;
  hi2.u = h & 0xffff0000u;
  l = pkrn(a - lo.f, b - hi2.f);
}

// ---- shared distance: identical instruction sequence everywhere (bit-exact re-eval) ----
__device__ __forceinline__ float dist4(const float4 q, const float4 c) {
  float t = __fmaf_rn(q.x, c.x, __fmaf_rn(q.y, c.y, __fmul_rn(q.z, c.z)));
  return __fmaf_rn(-2.f, t, q.w + c.w);
}

// ================= setup: prep(pkg) + wprep(weight frags) + xpose(xin planes) =============
__global__ __launch_bounds__(256) void setup_kernel(
    const float* __restrict__ p, const float* __restrict__ x,
    const float* __restrict__ d2W, const float* __restrict__ g1W,
    const float* __restrict__ g2W, const float* __restrict__ topW,
    const float* __restrict__ phiW, const float* __restrict__ psiW,
    const float* __restrict__ alpW, const float* __restrict__ dnW,
    float4* __restrict__ pkg, unsigned short* __restrict__ wpk,
    unsigned short* __restrict__ xh, unsigned short* __restrict__ xl)
{
  __shared__ float t[64][65];
  const int bid = blockIdx.x, tid = threadIdx.x;
  if (bid < 64) {            // ---- prep ----
    int i = bid * 256 + tid;
    int b = i >> 12, m = i & (NN - 1);
    const float* pb = p + (size_t)b * 3 * NN;
    float xx = pb[m], yy = pb[NN + m], zz = pb[2 * NN + m];
    pkg[i] = make_float4(xx, yy, zz, __fmaf_rn(xx, xx, __fmaf_rn(yy, yy, __fmul_rn(zz, zz))));
  } else if (bid < 128) {    // ---- wprep: mats 0=d2 1=g1 2=g2 3=top 4=phi 5=psi 6=alpha 7=down
    int tt = (bid - 64) * 256 + tid;       // 0..16383
    int mat = tt >> 11, r = tt & 2047;
    int ct = r >> 8, ks = (r >> 6) & 3, lane = r & 63;
    const float* W;
    switch (mat) {
      case 0: W = d2W; break;  case 1: W = g1W; break;
      case 2: W = g2W; break;  case 3: W = topW; break;
      case 4: W = phiW; break; case 5: W = psiW; break;
      case 6: W = alpW; break; default: W = dnW; break;
    }
    int row = ct * 16 + (lane & 15);
    int k0 = ks * 32 + (lane >> 4) * 8;
    const float* src = &W[row * 128 + k0];
    unsigned short* dh = &wpk[((size_t)(((mat * 2 + 0) * 8 + ct) * 4 + ks) * 64 + lane) * 8];
    unsigned short* dl = &wpk[((size_t)(((mat * 2 + 1) * 8 + ct) * 4 + ks) * 64 + lane) * 8];
#pragma unroll
    for (int e = 0; e < 8; ++e) {
      float v = src[e];
      unsigned short h = f2b(v);
      dh[e] = h;
      dl[e] = f2b(v - b2f(h));
    }
  } else {                   // ---- xpose: input_x [B][C][N] -> hi/lo planes [B][N][C]
    int bid2 = bid - 128;
    int nb = bid2 & 63, cb = (bid2 >> 6) & 1, b = bid2 >> 7;
    const int c0 = cb * 64, n0 = nb * 64;
    const int tn = tid & 63, tq = tid >> 6;
    const float* xb = x + ((size_t)b * CC + c0) * NN + n0;
#pragma unroll
    for (int i = 0; i < 16; ++i) {
      int c = tq * 16 + i;
      t[c][tn] = xb[(size_t)c * NN + tn];
    }
    __syncthreads();
#pragma unroll
    for (int i = 0; i < 16; ++i) {
      int nl = tq * 16 + i;
      float v = t[tn][nl];
      unsigned short h = f2b(v);
      size_t o = ((size_t)b * NN + n0 + nl) * CC + c0 + tn;
      xh[o] = h;
      xl[o] = f2b(v - b2f(h));
    }
  }
}

// ================= KNN: exact 16-NN set; per-wave LDS chunk staging + broadcast reads =====
__global__ __launch_bounds__(512, 2) void knn_kernel(const float4* __restrict__ pkg,
                                                     int* __restrict__ outidx)
{
  __shared__ float BD[8][64][17];
  __shared__ float4 CH[8][64];      // per-wave candidate chunk (8 KB)
  __shared__ float TS[64];
  __shared__ int   CNT[64];
  __shared__ float COLd[64][20];
  __shared__ int   COLi[64][20];
  const int b = blockIdx.y;
  const int tid = threadIdx.x;
  const int lane = tid & 63;        // query within block
  const int w = tid >> 6;           // wave 0..7
  const int n = blockIdx.x * 64 + lane;
  const float4* PB = pkg + (size_t)b * NN;
  const float4 qc = PB[n];
  if (tid < 64) CNT[tid] = 0;

  float bd[16];
#pragma unroll
  for (int t = 0; t < 16; ++t) bd[t] = FLT_BIG;
  const int m0 = w * 512;

  // ---- pass 1: per-wave top-16 distances (unconditional med3 ripple, LDS-staged) ----
  {
    float4 nxt = PB[m0 + lane];
    for (int c = 0; c < 8; ++c) {
      CH[w][lane] = nxt;                       // same-wave DS ordering: prior reads done
      if (c < 7) nxt = PB[m0 + (c + 1) * 64 + lane];
#pragma unroll 4
      for (int e = 0; e < 64; ++e) {
        float4 cd = CH[w][e];                  // wave-uniform addr -> broadcast
        float d = dist4(qc, cd);
#pragma unroll
        for (int t = 15; t >= 1; --t) bd[t] = __builtin_amdgcn_fmed3f(bd[t - 1], d, bd[t]);
        bd[0] = fminf(bd[0], d);
      }
    }
  }
#pragma unroll
  for (int t = 0; t < 16; ++t) BD[w][lane][t] = bd[t];
  __syncthreads();

  // ---- 8-way merge of sorted value lists: T = 16th smallest of union ----
  if (tid < 64) {
    const int q = tid;
    int h0 = 0, h1 = 0, h2 = 0, h3 = 0, h4 = 0, h5 = 0, h6 = 0, h7 = 0;
    float mv = FLT_BIG;
#pragma unroll 1
    for (int r = 0; r < 16; ++r) {
      float v0 = BD[0][q][h0], v1 = BD[1][q][h1], v2 = BD[2][q][h2], v3 = BD[3][q][h3];
      float v4 = BD[4][q][h4], v5 = BD[5][q][h5], v6 = BD[6][q][h6], v7 = BD[7][q][h7];
      mv = v0; int mw = 0;
      if (v1 < mv) { mv = v1; mw = 1; }
      if (v2 < mv) { mv = v2; mw = 2; }
      if (v3 < mv) { mv = v3; mw = 3; }
      if (v4 < mv) { mv = v4; mw = 4; }
      if (v5 < mv) { mv = v5; mw = 5; }
      if (v6 < mv) { mv = v6; mw = 6; }
      if (v7 < mv) { mv = v7; mw = 7; }
      h0 += (mw == 0); h1 += (mw == 1); h2 += (mw == 2); h3 += (mw == 3);
      h4 += (mw == 4); h5 += (mw == 5); h6 += (mw == 6); h7 += (mw == 7);
    }
    TS[q] = mv;
  }
  __syncthreads();

  // ---- pass 2: collect all candidates with d <= T (bit-identical d, LDS-staged) ----
  {
    const float thr = TS[lane];
    float4 nxt = PB[m0 + lane];
    for (int c = 0; c < 8; ++c) {
      CH[w][lane] = nxt;
      if (c < 7) nxt = PB[m0 + (c + 1) * 64 + lane];
#pragma unroll 4
      for (int e = 0; e < 64; ++e) {
        float4 cd = CH[w][e];
        float d = dist4(qc, cd);
        if (d <= thr) {
          int pos = atomicAdd(&CNT[lane], 1);
          if (pos < 20) { COLd[lane][pos] = d; COLi[lane][pos] = m0 + c * 64 + e; }
        }
      }
    }
  }
  __syncthreads();

  // ---- writeout (set semantics; exact boundary-tie rule on cold path) ----
  if (tid < 64) {
    const int q = tid;
    int c = CNT[q]; if (c > 20) c = 20;
    int* op = outidx + ((size_t)b * NN + blockIdx.x * 64 + q) * KK;
    if (c == KK) {
#pragma unroll
      for (int o = 0; o < KK; ++o) op[o] = COLi[q][o];
    } else {
      const float T = TS[q];
      int less = 0;
      for (int s = 0; s < c; ++s) less += (COLd[q][s] < T);
      int need = KK - less;
      int o = 0;
      for (int s = 0; s < c; ++s)
        if (COLd[q][s] < T) op[o++] = COLi[q][s];
      for (int s = 0; s < c; ++s) {
        if (COLd[q][s] == T) {
          int idx = COLi[q][s];
          int rank = 0;
          for (int s2 = 0; s2 < c; ++s2)
            rank += (COLd[q][s2] == T && COLi[q][s2] < idx);
          if (rank < need) op[o++] = idx;
        }
      }
    }
  }
}

// ================= feat: x = top(xin) in LDS; then phi/psi (f32) + alpha (bf16) ==========
__global__ __launch_bounds__(256) void feat_kernel(
    const unsigned short* __restrict__ xh, const unsigned short* __restrict__ xl,
    const unsigned short* __restrict__ wpk,
    const float* __restrict__ topb, const float* __restrict__ phib,
    const float* __restrict__ psib, const float* __restrict__ alpb,
    float* __restrict__ phit, float* __restrict__ psit,
    unsigned short* __restrict__ alpt)
{
  __shared__ float xtile[32][129];
  const int b = blockIdx.y, n0 = blockIdx.x * 32;
  const int tid = threadIdx.x, l = tid & 63, w = tid >> 6;
  const int lr = l & 15, lh = l >> 4;
  const int nt = w & 1, cq = w >> 1;
  // ---- phase 1: x rows (nt half) into LDS ----
  {
    const int nrow = n0 + nt * 16 + lr;
    const unsigned short* xhp = xh + ((size_t)b * NN + nrow) * CC;
    const unsigned short* xlp = xl + ((size_t)b * NN + nrow) * CC;
    short8v Ah[4], Al[4];
#pragma unroll
    for (int ks = 0; ks < 4; ++ks) {
      Ah[ks] = *(const short8v*)&xhp[ks * 32 + lh * 8];
      Al[ks] = *(const short8v*)&xlp[ks * 32 + lh * 8];
    }
    const int nDl = nt * 16 + lh * 4;
#pragma unroll
    for (int cc = 0; cc < 4; ++cc) {
      const int colt = cq * 4 + cc;
      f32x4 acc = (f32x4){0.f, 0.f, 0.f, 0.f};
#pragma unroll
      for (int ks = 0; ks < 4; ++ks) {
        short8v Wh = *(const short8v*)&wpk[((size_t)(((3 * 2 + 0) * 8 + colt) * 4 + ks) * 64 + l) * 8];
        short8v Wl = *(const short8v*)&wpk[((size_t)(((3 * 2 + 1) * 8 + colt) * 4 + ks) * 64 + l) * 8];
        acc = __builtin_amdgcn_mfma_f32_16x16x32_bf16(Ah[ks], Wh, acc, 0, 0, 0);
        acc = __builtin_amdgcn_mfma_f32_16x16x32_bf16(Al[ks], Wh, acc, 0, 0, 0);
        acc = __builtin_amdgcn_mfma_f32_16x16x32_bf16(Ah[ks], Wl, acc, 0, 0, 0);
      }
      float bv = topb[colt * 16 + lr];
#pragma unroll
      for (int r = 0; r < 4; ++r) xtile[nDl + r][colt * 16 + lr] = acc[r] + bv;
    }
  }
  __syncthreads();
  // ---- phase 2: rebuild pair A-frags from LDS, run phi/psi/alpha ----
  short8v Ah[4], Al[4];
  {
    const int rl = nt * 16 + lr;
#pragma unroll
    for (int ks = 0; ks < 4; ++ks) {
      union { short8v s; unsigned u[4]; } H, L;
#pragma unroll
      for (int i = 0; i < 4; ++i) {
        float a = xtile[rl][ks * 32 + lh * 8 + 2 * i];
        float bb = xtile[rl][ks * 32 + lh * 8 + 2 * i + 1];
        split2(a, bb, H.u[i], L.u[i]);
      }
      Ah[ks] = H.s; Al[ks] = L.s;
    }
  }
  const int nD = n0 + nt * 16 + lh * 4;
#pragma unroll
  for (int m = 0; m < 3; ++m) {
    const int mat = 4 + m;
    const float* bias = (m == 0) ? phib : (m == 1) ? psib : alpb;
#pragma unroll
    for (int cc = 0; cc < 4; ++cc) {
      const int colt = cq * 4 + cc;
      f32x4 acc = (f32x4){0.f, 0.f, 0.f, 0.f};
#pragma unroll
      for (int ks = 0; ks < 4; ++ks) {
        short8v Wh = *(const short8v*)&wpk[((size_t)(((mat * 2 + 0) * 8 + colt) * 4 + ks) * 64 + l) * 8];
        short8v Wl = *(const short8v*)&wpk[((size_t)(((mat * 2 + 1) * 8 + colt) * 4 + ks) * 64 + l) * 8];
        acc = __builtin_amdgcn_mfma_f32_16x16x32_bf16(Ah[ks], Wh, acc, 0, 0, 0);
        acc = __builtin_amdgcn_mfma_f32_16x16x32_bf16(Al[ks], Wh, acc, 0, 0, 0);
        acc = __builtin_amdgcn_mfma_f32_16x16x32_bf16(Ah[ks], Wl, acc, 0, 0, 0);
      }
      float bv = bias[colt * 16 + lr];
      if (m == 2) {
#pragma unroll
        for (int r = 0; r < 4; ++r)
          alpt[((size_t)b * NN + nD + r) * CC + colt * 16 + lr] = f2b(acc[r] + bv);
      } else {
        float* outp = (m == 0) ? phit : psit;
#pragma unroll
        for (int r = 0; r < 4; ++r)
          outp[((size_t)b * NN + nD + r) * CC + colt * 16 + lr] = acc[r] + bv;
      }
    }
  }
}

// ================= down: out = dnW @ y + b + res  (y from pair planes) ==================
__global__ __launch_bounds__(256) void down_kernel(
    const unsigned short* __restrict__ yh, const unsigned short* __restrict__ yl,
    const unsigned short* __restrict__ wpk,
    const float* __restrict__ bias, const float* __restrict__ res,
    float* __restrict__ out)
{
  const int b = blockIdx.y, n0 = blockIdx.x * 64;
  const int tid = threadIdx.x, l = tid & 63, w = tid >> 6;
  const int lr = l & 15, lh = l >> 4;
  short8v Ah[2][4], Al[2][4];
#pragma unroll
  for (int ct = 0; ct < 2; ++ct)
#pragma unroll
    for (int ks = 0; ks < 4; ++ks) {
      Ah[ct][ks] = *(const short8v*)&wpk[((size_t)(((7 * 2 + 0) * 8 + (2 * w + ct)) * 4 + ks) * 64 + l) * 8];
      Al[ct][ks] = *(const short8v*)&wpk[((size_t)(((7 * 2 + 1) * 8 + (2 * w + ct)) * 4 + ks) * 64 + l) * 8];
    }
  f32x4 acc[2][4];
#pragma unroll
  for (int colt = 0; colt < 4; ++colt) {
    const int n = n0 + colt * 16 + lr;
    const unsigned short* yhp = yh + ((size_t)b * NN + n) * CC;
    const unsigned short* ylp = yl + ((size_t)b * NN + n) * CC;
#pragma unroll
    for (int ct = 0; ct < 2; ++ct) acc[ct][colt] = (f32x4){0.f, 0.f, 0.f, 0.f};
#pragma unroll
    for (int ks = 0; ks < 4; ++ks) {
      short8v Bh = *(const short8v*)&yhp[ks * 32 + lh * 8];
      short8v Bl = *(const short8v*)&ylp[ks * 32 + lh * 8];
#pragma unroll
      for (int ct = 0; ct < 2; ++ct) {
        acc[ct][colt] = __builtin_amdgcn_mfma_f32_16x16x32_bf16(Ah[ct][ks], Bh, acc[ct][colt], 0, 0, 0);
        acc[ct][colt] = __builtin_amdgcn_mfma_f32_16x16x32_bf16(Ah[ct][ks], Bl, acc[ct][colt], 0, 0, 0);
        acc[ct][colt] = __builtin_amdgcn_mfma_f32_16x16x32_bf16(Al[ct][ks], Bh, acc[ct][colt], 0, 0, 0);
      }
    }
  }
#pragma unroll
  for (int ct = 0; ct < 2; ++ct) {
    const int c0 = 32 * w + ct * 16 + lh * 4;
#pragma unroll
    for (int r = 0; r < 4; ++r) {
      float bv = bias[c0 + r];
#pragma unroll
      for (int colt = 0; colt < 4; ++colt) {
        size_t o = ((size_t)b * CC + c0 + r) * NN + n0 + colt * 16 + lr;
        out[o] = acc[ct][colt][r] + bv + res[o];
      }
    }
  }
}

// ================= Fused core: act XOR-swizzle, inline gathers, bcast-softmax ============
#define TNP 4
// swizzle: XOR 16-B chunk index (bits 3..5 of halfword idx) with row&7 -> <=2-way banks
#define ASW(row, c) ((c) ^ (((row) & 7) << 3))
__global__ __launch_bounds__(256, 4) void fused_kernel(
    const float* __restrict__ p, const int* __restrict__ idxg,
    const float* __restrict__ phi_t, const float* __restrict__ psi_t,
    const unsigned short* __restrict__ alp_b, const unsigned short* __restrict__ wpk,
    const float* __restrict__ d1W, const float* __restrict__ d1b,
    const float* __restrict__ d2b, const float* __restrict__ g1b,
    const float* __restrict__ g2b,
    unsigned short* __restrict__ yh, unsigned short* __restrict__ yl)
{
  __shared__ __align__(16) unsigned short act[2][64][136];  // [hi/lo][col][c]
  __shared__ int idxs[64];
  const int b = blockIdx.y;
  const int n0 = blockIdx.x * TNP;
  const int tid = threadIdx.x;
  const int l = tid & 63, w = tid >> 6;
  const int lr = l & 15, lh = l >> 4;

  if (tid < 64) idxs[tid] = idxg[((size_t)b * NN + n0 + (tid >> 4)) * KK + (tid & 15)];
  __syncthreads();

  // ---------- stage 0: rel -> pos1 = relu(d1W rel + d1b), hi/lo into act ----------
  {
    const int col = tid & 63, q = tid >> 6;
    const int pt = col >> 4;
    const int j = idxs[col];
    const float* pb = p + (size_t)b * 3 * NN;
    float r0 = pb[n0 + pt] - pb[j];
    float r1 = pb[NN + n0 + pt] - pb[NN + j];
    float r2 = pb[2 * NN + n0 + pt] - pb[2 * NN + j];
#pragma unroll
    for (int ch = 0; ch < 4; ++ch) {
      int c0 = q * 32 + ch * 8;
      float v[8];
#pragma unroll
      for (int e = 0; e < 8; ++e) {
        int c = c0 + e;
        v[e] = fmaxf(d1W[c * 3 + 0] * r0 + d1W[c * 3 + 1] * r1 + d1W[c * 3 + 2] * r2 + d1b[c], 0.f);
      }
      uint4 H, L;
      split2(v[0], v[1], H.x, L.x); split2(v[2], v[3], H.y, L.y);
      split2(v[4], v[5], H.z, L.z); split2(v[6], v[7], H.w, L.w);
      *(uint4*)&act[0][col][ASW(col, c0)] = H;
      *(uint4*)&act[1][col][ASW(col, c0)] = L;
    }
  }
  __syncthreads();

  int idxv[TNP];
#pragma unroll
  for (int colt = 0; colt < TNP; ++colt) idxv[colt] = idxs[colt * 16 + lr];

  f32x4 acc[2][TNP];
  short8v Af[2][4];

#define LOADA(MAT) do {                                                                 \
  _Pragma("unroll") for (int ct = 0; ct < 2; ++ct)                                      \
    _Pragma("unroll") for (int ks = 0; ks < 4; ++ks)                                    \
      Af[ct][ks] = *(const short8v*)&wpk[((size_t)((((MAT) * 2 + 0) * 8 + (2 * w + ct)) * 4 + ks) * 64 + l) * 8]; \
  } while (0)

#define MMUL() do {                                                                     \
  _Pragma("unroll") for (int ct = 0; ct < 2; ++ct)                                      \
    _Pragma("unroll") for (int colt = 0; colt < TNP; ++colt)                            \
      acc[ct][colt] = (f32x4){0.f, 0.f, 0.f, 0.f};                                      \
  _Pragma("unroll") for (int colt = 0; colt < TNP; ++colt) {                            \
    const int row_ = colt * 16 + lr;                                                    \
    short8v Bh[4], Bl[4];                                                               \
    _Pragma("unroll") for (int ks = 0; ks < 4; ++ks) {                                  \
      Bh[ks] = *(const short8v*)&act[0][row_][ASW(row_, ks * 32 + lh * 8)];             \
      Bl[ks] = *(const short8v*)&act[1][row_][ASW(row_, ks * 32 + lh * 8)];             \
    }                                                                                   \
    _Pragma("unroll") for (int ct = 0; ct < 2; ++ct)                                    \
      _Pragma("unroll") for (int ks = 0; ks < 4; ++ks) {                                \
        acc[ct][colt] = __builtin_amdgcn_mfma_f32_16x16x32_bf16(Af[ct][ks], Bh[ks],     \
                                                                acc[ct][colt], 0, 0, 0); \
        acc[ct][colt] = __builtin_amdgcn_mfma_f32_16x16x32_bf16(Af[ct][ks], Bl[ks],     \
                                                                acc[ct][colt], 0, 0, 0); \
      }                                                                                 \
  } } while (0)

  // ---------- d2: pos = d2W @ pos1 + d2b (kept in registers) ----------
  LOADA(0); MMUL();
  float pos[2][TNP][4];
#pragma unroll
  for (int ct = 0; ct < 2; ++ct) {
    f32x4 bv = *(const f32x4*)&d2b[32 * w + ct * 16 + lh * 4];
#pragma unroll
    for (int colt = 0; colt < TNP; ++colt)
#pragma unroll
      for (int r = 0; r < 4; ++r) pos[ct][colt][r] = acc[ct][colt][r] + bv[r];
  }
  __syncthreads();   // all waves done reading pos1

  // ---------- ain = pos + phi[n] - psi[idx] -> act (inline gathers) ----------
#pragma unroll
  for (int colt = 0; colt < TNP; ++colt) {
    size_t prow = ((size_t)b * NN + n0 + colt) * CC;
    size_t srow = ((size_t)b * NN + idxv[colt]) * CC;
#pragma unroll
    for (int ct = 0; ct < 2; ++ct) {
      int c0 = 32 * w + ct * 16 + lh * 4;
      f32x4 ph = *(const f32x4*)&phi_t[prow + c0];
      f32x4 ps = *(const f32x4*)&psi_t[srow + c0];
      float v[4];
#pragma unroll
      for (int r = 0; r < 4; ++r) v[r] = pos[ct][colt][r] + ph[r] - ps[r];
      uint2 H, L;
      split2(v[0], v[1], H.x, L.x); split2(v[2], v[3], H.y, L.y);
      const int row = colt * 16 + lr;
      *(uint2*)&act[0][row][ASW(row, c0)] = H;
      *(uint2*)&act[1][row][ASW(row, c0)] = L;
    }
  }
  __syncthreads();

  // ---------- g1: h = relu(g1W @ ain + g1b) -> act ----------
  LOADA(1); MMUL();
  __syncthreads();   // all waves done reading ain
#pragma unroll
  for (int ct = 0; ct < 2; ++ct) {
    f32x4 bv = *(const f32x4*)&g1b[32 * w + ct * 16 + lh * 4];
    int c0 = 32 * w + ct * 16 + lh * 4;
#pragma unroll
    for (int colt = 0; colt < TNP; ++colt) {
      float v[4];
#pragma unroll
      for (int r = 0; r < 4; ++r) v[r] = fmaxf(acc[ct][colt][r] + bv[r], 0.f);
      uint2 H, L;
      split2(v[0], v[1], H.x, L.x); split2(v[2], v[3], H.y, L.y);
      const int row = colt * 16 + lr;
      *(uint2*)&act[0][row][ASW(row, c0)] = H;
      *(uint2*)&act[1][row][ASW(row, c0)] = L;
    }
  }
  __syncthreads();

  // ---------- g2: attn = g2W @ h + g2b ----------
  LOADA(2); MMUL();
#pragma unroll
  for (int ct = 0; ct < 2; ++ct) {
    f32x4 bv = *(const f32x4*)&g2b[32 * w + ct * 16 + lh * 4];
#pragma unroll
    for (int colt = 0; colt < TNP; ++colt)
#pragma unroll
      for (int r = 0; r < 4; ++r) acc[ct][colt][r] += bv[r];
  }

  // ---------- softmax over k (= lr lanes, group base broadcast; shift-invariant) ----------
#pragma unroll
  for (int ct = 0; ct < 2; ++ct)
#pragma unroll
    for (int colt = 0; colt < TNP; ++colt)
#pragma unroll
      for (int r = 0; r < 4; ++r) {
        float a = acc[ct][colt][r];
        float m = __shfl(a, l & 48);          // group-base value (exact softmax shift)
        float e = __expf(a - m);
        float s = e;
        s += __shfl_xor(s, 1);
        s += __shfl_xor(s, 2);
        s += __shfl_xor(s, 4);
        s += __shfl_xor(s, 8);
        acc[ct][colt][r] = e * __builtin_amdgcn_rcpf(s);
      }

  __syncthreads();   // all waves past their last act read (g2 MMUL) -> safe to reuse act
  unsigned short* yst = &act[0][0][0];   // staging: rows 0..3 = yh[colt], rows 4..7 = yl

  // ---------- combine: y_t[n][c] = sum_k wgt * (alpha[idx] + pos) ----------
#pragma unroll
  for (int colt = 0; colt < TNP; ++colt) {
    size_t arow = ((size_t)b * NN + idxv[colt]) * CC;
#pragma unroll
    for (int ct = 0; ct < 2; ++ct) {
      int c0 = 32 * w + ct * 16 + lh * 4;
      uint2 ua = *(const uint2*)&alp_b[arow + c0];
      union { unsigned u; float f; } a0, a1, a2, a3;
      a0.u = ua.x << 16; a1.u = ua.x & 0xffff0000u;
      a2.u = ua.y << 16; a3.u = ua.y & 0xffff0000u;
      float av[4] = {a0.f, a1.f, a2.f, a3.f};
      float yv[4];
#pragma unroll
      for (int r = 0; r < 4; ++r) {
        float part = acc[ct][colt][r] * (av[r] + pos[ct][colt][r]);
        part += __shfl_xor(part, 1);
        part += __shfl_xor(part, 2);
        part += __shfl_xor(part, 4);
        part += __shfl_xor(part, 8);
        yv[r] = part;
      }
      if (lr == 0) {
        uint2 H, L;
        split2(yv[0], yv[1], H.x, L.x); split2(yv[2], yv[3], H.y, L.y);
        *(uint2*)&yst[(size_t)colt * 128 + c0] = H;
        *(uint2*)&yst[(size_t)(4 + colt) * 128 + c0] = L;
      }
    }
  }
  __syncthreads();
  // ---------- coalesced y writeout: 2 KB, 16B per thread ----------
  if (tid < 128) {
    int plane = tid >> 6, row = (tid >> 4) & 3, chunk = tid & 15;
    uint4 v4 = *(const uint4*)&yst[(size_t)(plane * 4 + row) * 128 + chunk * 8];
    unsigned short* dst = (plane ? yl : yh) + ((size_t)b * NN + n0 + row) * CC + chunk * 8;
    *(uint4*)dst = v4;
  }
#undef LOADA
#undef MMUL
}

// =============================================================================================
extern "C" void kernel_launch(void* const* d_in, const int* in_sizes, int n_in,
                              void* d_out, int out_size, void* d_ws, size_t ws_size,
                              hipStream_t stream) {
  const float* input_p = (const float*)d_in[0];
  const float* input_x = (const float*)d_in[1];
  const float* top_W   = (const float*)d_in[2];  const float* top_b   = (const float*)d_in[3];
  const float* down_W  = (const float*)d_in[4];  const float* down_b  = (const float*)d_in[5];
  const float* phi_W   = (const float*)d_in[6];  const float* phi_b   = (const float*)d_in[7];
  const float* psi_W   = (const float*)d_in[8];  const float* psi_b   = (const float*)d_in[9];
  const float* alpha_W = (const float*)d_in[10]; const float* alpha_b = (const float*)d_in[11];
  const float* g1_W    = (const float*)d_in[12]; const float* g1_b    = (const float*)d_in[13];
  const float* g2_W    = (const float*)d_in[14]; const float* g2_b    = (const float*)d_in[15];
  const float* d1_W    = (const float*)d_in[16]; const float* d1_b    = (const float*)d_in[17];
  const float* d2_W    = (const float*)d_in[18]; const float* d2_b    = (const float*)d_in[19];
  float* out = (float*)d_out;

  char* ws = (char*)d_ws;
  int*            ws_idx   = (int*)ws;                                         // 1 MB
  unsigned short* ws_xin_h = (unsigned short*)(ws + (size_t)1  * (1 << 20));   // 4 MB (reused as y_h)
  unsigned short* ws_xin_l = (unsigned short*)(ws + (size_t)5  * (1 << 20));   // 4 MB (reused as y_l)
  float*          ws_phi   = (float*)(ws + (size_t)9  * (1 << 20));            // 8 MB
  float*          ws_psi   = (float*)(ws + (size_t)17 * (1 << 20));            // 8 MB
  unsigned short* ws_alp   = (unsigned short*)(ws + (size_t)25 * (1 << 20));   // 4 MB (bf16)
  float4*         ws_pkg   = (float4*)(ws + (size_t)29 * (1 << 20));           // 256 KB
  unsigned short* ws_wpk   = (unsigned short*)(ws + (size_t)29 * (1 << 20) + (1 << 18)); // 512 KB
  unsigned short* ws_y_h = ws_xin_h;   // xin consumed by feat; stream-ordered reuse
  unsigned short* ws_y_l = ws_xin_l;

  setup_kernel<<<640, 256, 0, stream>>>(input_p, input_x, d2_W, g1_W, g2_W, top_W,
                                        phi_W, psi_W, alpha_W, down_W,
                                        ws_pkg, ws_wpk, ws_xin_h, ws_xin_l);
  knn_kernel<<<dim3(NN / 64, BB), 512, 0, stream>>>(ws_pkg, ws_idx);
  feat_kernel<<<dim3(NN / 32, BB), 256, 0, stream>>>(ws_xin_h, ws_xin_l, ws_wpk,
                                                     top_b, phi_b, psi_b, alpha_b,
                                                     ws_phi, ws_psi, ws_alp);
  fused_kernel<<<dim3(NN / TNP, BB), 256, 0, stream>>>(input_p, ws_idx, ws_phi, ws_psi, ws_alp,
                                                       ws_wpk, d1_W, d1_b, d2_b, g1_b, g2_b,
                                                       ws_y_h, ws_y_l);
  down_kernel<<<dim3(NN / 64, BB), 256, 0, stream>>>(ws_y_h, ws_y_l, ws_wpk, down_b,
                                                     input_x, out);
}

// Round 10
// 322.084 us; speedup vs baseline: 1.3588x; 1.1453x over previous
//
#include <hip/hip_runtime.h>
#include <hip/hip_bf16.h>

#define BB 4
#define CC 128
#define NN 4096
#define KK 16
#define FLT_BIG 3.402823466e+38f

typedef __attribute__((ext_vector_type(8))) short short8v;
typedef __attribute__((ext_vector_type(4))) short short4v;
typedef __attribute__((ext_vector_type(4))) float f32x4;

__device__ __forceinline__ unsigned short f2b(float x) {   // RNE f32->bf16 (manual)
  union { float f; unsigned u; } v; v.f = x;
  unsigned r = v.u + 0x7fffu + ((v.u >> 16) & 1u);
  return (unsigned short)(r >> 16);
}
__device__ __forceinline__ float b2f(unsigned short h) {
  union { float f; unsigned u; } v; v.u = ((unsigned)h) << 16; return v.f;
}
// packed RNE pair: [15:0]=bf16(a), [31:16]=bf16(b)  (v_cvt_pk_bf16_f32)
__device__ __forceinline__ unsigned pkrn(float a, float b) {
  __hip_bfloat162 t = __float22bfloat162_rn(make_float2(a, b));
  union { __hip_bfloat162 h; unsigned u; } c; c.h = t; return c.u;
}
// split (a,b) into packed hi + packed lo bf16 pairs
__device__ __forceinline__ void split2(float a, float b, unsigned& h, unsigned& l) {
  h = pkrn(a, b);
  union { unsigned u; float f; } lo, hi2;
  lo.u = h << 16;
  hi2.u = h & 0xffff0000u;
  l = pkrn(a - lo.f, b - hi2.f);
}

// ---- shared distance: identical instruction sequence everywhere (bit-exact re-eval) ----
__device__ __forceinline__ float dist4(const float4 q, const float4 c) {
  float t = __fmaf_rn(q.x, c.x, __fmaf_rn(q.y, c.y, __fmul_rn(q.z, c.z)));
  return __fmaf_rn(-2.f, t, q.w + c.w);
}

// ================= setup: prep(pkg) + wprep(weight frags) + xpose(xin planes) =============
__global__ __launch_bounds__(256) void setup_kernel(
    const float* __restrict__ p, const float* __restrict__ x,
    const float* __restrict__ d2W, const float* __restrict__ g1W,
    const float* __restrict__ g2W, const float* __restrict__ topW,
    const float* __restrict__ phiW, const float* __restrict__ psiW,
    const float* __restrict__ alpW, const float* __restrict__ dnW,
    float4* __restrict__ pkg, unsigned short* __restrict__ wpk,
    unsigned short* __restrict__ xh, unsigned short* __restrict__ xl)
{
  __shared__ float t[64][65];
  const int bid = blockIdx.x, tid = threadIdx.x;
  if (bid < 64) {            // ---- prep ----
    int i = bid * 256 + tid;
    int b = i >> 12, m = i & (NN - 1);
    const float* pb = p + (size_t)b * 3 * NN;
    float xx = pb[m], yy = pb[NN + m], zz = pb[2 * NN + m];
    pkg[i] = make_float4(xx, yy, zz, __fmaf_rn(xx, xx, __fmaf_rn(yy, yy, __fmul_rn(zz, zz))));
  } else if (bid < 128) {    // ---- wprep: mats 0=d2 1=g1 2=g2 3=top 4=phi 5=psi 6=alpha 7=down
    int tt = (bid - 64) * 256 + tid;       // 0..16383
    int mat = tt >> 11, r = tt & 2047;
    int ct = r >> 8, ks = (r >> 6) & 3, lane = r & 63;
    const float* W;
    switch (mat) {
      case 0: W = d2W; break;  case 1: W = g1W; break;
      case 2: W = g2W; break;  case 3: W = topW; break;
      case 4: W = phiW; break; case 5: W = psiW; break;
      case 6: W = alpW; break; default: W = dnW; break;
    }
    int row = ct * 16 + (lane & 15);
    int k0 = ks * 32 + (lane >> 4) * 8;
    const float* src = &W[row * 128 + k0];
    unsigned short* dh = &wpk[((size_t)(((mat * 2 + 0) * 8 + ct) * 4 + ks) * 64 + lane) * 8];
    unsigned short* dl = &wpk[((size_t)(((mat * 2 + 1) * 8 + ct) * 4 + ks) * 64 + lane) * 8];
#pragma unroll
    for (int e = 0; e < 8; ++e) {
      float v = src[e];
      unsigned short h = f2b(v);
      dh[e] = h;
      dl[e] = f2b(v - b2f(h));
    }
  } else {                   // ---- xpose: input_x [B][C][N] -> hi/lo planes [B][N][C]
    int bid2 = bid - 128;
    int nb = bid2 & 63, cb = (bid2 >> 6) & 1, b = bid2 >> 7;
    const int c0 = cb * 64, n0 = nb * 64;
    const int tn = tid & 63, tq = tid >> 6;
    const float* xb = x + ((size_t)b * CC + c0) * NN + n0;
#pragma unroll
    for (int i = 0; i < 16; ++i) {
      int c = tq * 16 + i;
      t[c][tn] = xb[(size_t)c * NN + tn];
    }
    __syncthreads();
#pragma unroll
    for (int i = 0; i < 16; ++i) {
      int nl = tq * 16 + i;
      float v = t[tn][nl];
      unsigned short h = f2b(v);
      size_t o = ((size_t)b * NN + n0 + nl) * CC + c0 + tn;
      xh[o] = h;
      xl[o] = f2b(v - b2f(h));
    }
  }
}

// ================= KNN: exact 16-NN set; per-wave LDS chunk staging + broadcast reads =====
__global__ __launch_bounds__(512, 2) void knn_kernel(const float4* __restrict__ pkg,
                                                     int* __restrict__ outidx)
{
  __shared__ float BD[8][64][17];
  __shared__ float4 CH[8][64];      // per-wave candidate chunk (8 KB)
  __shared__ float TS[64];
  __shared__ int   CNT[64];
  __shared__ float COLd[64][20];
  __shared__ int   COLi[64][20];
  const int b = blockIdx.y;
  const int tid = threadIdx.x;
  const int lane = tid & 63;        // query within block
  const int w = tid >> 6;           // wave 0..7
  const int n = blockIdx.x * 64 + lane;
  const float4* PB = pkg + (size_t)b * NN;
  const float4 qc = PB[n];
  if (tid < 64) CNT[tid] = 0;

  float bd[16];
#pragma unroll
  for (int t = 0; t < 16; ++t) bd[t] = FLT_BIG;
  const int m0 = w * 512;

  // ---- pass 1: per-wave top-16 distances (unconditional med3 ripple, LDS-staged) ----
  {
    float4 nxt = PB[m0 + lane];
    for (int c = 0; c < 8; ++c) {
      CH[w][lane] = nxt;                       // same-wave DS ordering: prior reads done
      if (c < 7) nxt = PB[m0 + (c + 1) * 64 + lane];
#pragma unroll 4
      for (int e = 0; e < 64; ++e) {
        float4 cd = CH[w][e];                  // wave-uniform addr -> broadcast
        float d = dist4(qc, cd);
#pragma unroll
        for (int t = 15; t >= 1; --t) bd[t] = __builtin_amdgcn_fmed3f(bd[t - 1], d, bd[t]);
        bd[0] = fminf(bd[0], d);
      }
    }
  }
#pragma unroll
  for (int t = 0; t < 16; ++t) BD[w][lane][t] = bd[t];
  __syncthreads();

  // ---- 8-way merge of sorted value lists: T = 16th smallest of union ----
  if (tid < 64) {
    const int q = tid;
    int h0 = 0, h1 = 0, h2 = 0, h3 = 0, h4 = 0, h5 = 0, h6 = 0, h7 = 0;
    float mv = FLT_BIG;
#pragma unroll 1
    for (int r = 0; r < 16; ++r) {
      float v0 = BD[0][q][h0], v1 = BD[1][q][h1], v2 = BD[2][q][h2], v3 = BD[3][q][h3];
      float v4 = BD[4][q][h4], v5 = BD[5][q][h5], v6 = BD[6][q][h6], v7 = BD[7][q][h7];
      mv = v0; int mw = 0;
      if (v1 < mv) { mv = v1; mw = 1; }
      if (v2 < mv) { mv = v2; mw = 2; }
      if (v3 < mv) { mv = v3; mw = 3; }
      if (v4 < mv) { mv = v4; mw = 4; }
      if (v5 < mv) { mv = v5; mw = 5; }
      if (v6 < mv) { mv = v6; mw = 6; }
      if (v7 < mv) { mv = v7; mw = 7; }
      h0 += (mw == 0); h1 += (mw == 1); h2 += (mw == 2); h3 += (mw == 3);
      h4 += (mw == 4); h5 += (mw == 5); h6 += (mw == 6); h7 += (mw == 7);
    }
    TS[q] = mv;
  }
  __syncthreads();

  // ---- pass 2: collect all candidates with d <= T (bit-identical d, LDS-staged) ----
  {
    const float thr = TS[lane];
    float4 nxt = PB[m0 + lane];
    for (int c = 0; c < 8; ++c) {
      CH[w][lane] = nxt;
      if (c < 7) nxt = PB[m0 + (c + 1) * 64 + lane];
#pragma unroll 4
      for (int e = 0; e < 64; ++e) {
        float4 cd = CH[w][e];
        float d = dist4(qc, cd);
        if (d <= thr) {
          int pos = atomicAdd(&CNT[lane], 1);
          if (pos < 20) { COLd[lane][pos] = d; COLi[lane][pos] = m0 + c * 64 + e; }
        }
      }
    }
  }
  __syncthreads();

  // ---- writeout (set semantics; exact boundary-tie rule on cold path) ----
  if (tid < 64) {
    const int q = tid;
    int c = CNT[q]; if (c > 20) c = 20;
    int* op = outidx + ((size_t)b * NN + blockIdx.x * 64 + q) * KK;
    if (c == KK) {
#pragma unroll
      for (int o = 0; o < KK; ++o) op[o] = COLi[q][o];
    } else {
      const float T = TS[q];
      int less = 0;
      for (int s = 0; s < c; ++s) less += (COLd[q][s] < T);
      int need = KK - less;
      int o = 0;
      for (int s = 0; s < c; ++s)
        if (COLd[q][s] < T) op[o++] = COLi[q][s];
      for (int s = 0; s < c; ++s) {
        if (COLd[q][s] == T) {
          int idx = COLi[q][s];
          int rank = 0;
          for (int s2 = 0; s2 < c; ++s2)
            rank += (COLd[q][s2] == T && COLi[q][s2] < idx);
          if (rank < need) op[o++] = idx;
        }
      }
    }
  }
}

// ================= feat: x = top(xin) in LDS; then phi (f32) + psi/alpha (bf16) ==========
__global__ __launch_bounds__(256) void feat_kernel(
    const unsigned short* __restrict__ xh, const unsigned short* __restrict__ xl,
    const unsigned short* __restrict__ wpk,
    const float* __restrict__ topb, const float* __restrict__ phib,
    const float* __restrict__ psib, const float* __restrict__ alpb,
    float* __restrict__ phit, unsigned short* __restrict__ psit,
    unsigned short* __restrict__ alpt)
{
  __shared__ float xtile[32][129];
  const int b = blockIdx.y, n0 = blockIdx.x * 32;
  const int tid = threadIdx.x, l = tid & 63, w = tid >> 6;
  const int lr = l & 15, lh = l >> 4;
  const int nt = w & 1, cq = w >> 1;
  // ---- phase 1: x rows (nt half) into LDS ----
  {
    const int nrow = n0 + nt * 16 + lr;
    const unsigned short* xhp = xh + ((size_t)b * NN + nrow) * CC;
    const unsigned short* xlp = xl + ((size_t)b * NN + nrow) * CC;
    short8v Ah[4], Al[4];
#pragma unroll
    for (int ks = 0; ks < 4; ++ks) {
      Ah[ks] = *(const short8v*)&xhp[ks * 32 + lh * 8];
      Al[ks] = *(const short8v*)&xlp[ks * 32 + lh * 8];
    }
    const int nDl = nt * 16 + lh * 4;
#pragma unroll
    for (int cc = 0; cc < 4; ++cc) {
      const int colt = cq * 4 + cc;
      f32x4 acc = (f32x4){0.f, 0.f, 0.f, 0.f};
#pragma unroll
      for (int ks = 0; ks < 4; ++ks) {
        short8v Wh = *(const short8v*)&wpk[((size_t)(((3 * 2 + 0) * 8 + colt) * 4 + ks) * 64 + l) * 8];
        short8v Wl = *(const short8v*)&wpk[((size_t)(((3 * 2 + 1) * 8 + colt) * 4 + ks) * 64 + l) * 8];
        acc = __builtin_amdgcn_mfma_f32_16x16x32_bf16(Ah[ks], Wh, acc, 0, 0, 0);
        acc = __builtin_amdgcn_mfma_f32_16x16x32_bf16(Al[ks], Wh, acc, 0, 0, 0);
        acc = __builtin_amdgcn_mfma_f32_16x16x32_bf16(Ah[ks], Wl, acc, 0, 0, 0);
      }
      float bv = topb[colt * 16 + lr];
#pragma unroll
      for (int r = 0; r < 4; ++r) xtile[nDl + r][colt * 16 + lr] = acc[r] + bv;
    }
  }
  __syncthreads();
  // ---- phase 2: rebuild pair A-frags from LDS, run phi/psi/alpha ----
  short8v Ah[4], Al[4];
  {
    const int rl = nt * 16 + lr;
#pragma unroll
    for (int ks = 0; ks < 4; ++ks) {
      union { short8v s; unsigned u[4]; } H, L;
#pragma unroll
      for (int i = 0; i < 4; ++i) {
        float a = xtile[rl][ks * 32 + lh * 8 + 2 * i];
        float bb = xtile[rl][ks * 32 + lh * 8 + 2 * i + 1];
        split2(a, bb, H.u[i], L.u[i]);
      }
      Ah[ks] = H.s; Al[ks] = L.s;
    }
  }
  const int nD = n0 + nt * 16 + lh * 4;
#pragma unroll
  for (int m = 0; m < 3; ++m) {
    const int mat = 4 + m;
    const float* bias = (m == 0) ? phib : (m == 1) ? psib : alpb;
#pragma unroll
    for (int cc = 0; cc < 4; ++cc) {
      const int colt = cq * 4 + cc;
      f32x4 acc = (f32x4){0.f, 0.f, 0.f, 0.f};
#pragma unroll
      for (int ks = 0; ks < 4; ++ks) {
        short8v Wh = *(const short8v*)&wpk[((size_t)(((mat * 2 + 0) * 8 + colt) * 4 + ks) * 64 + l) * 8];
        short8v Wl = *(const short8v*)&wpk[((size_t)(((mat * 2 + 1) * 8 + colt) * 4 + ks) * 64 + l) * 8];
        acc = __builtin_amdgcn_mfma_f32_16x16x32_bf16(Ah[ks], Wh, acc, 0, 0, 0);
        acc = __builtin_amdgcn_mfma_f32_16x16x32_bf16(Al[ks], Wh, acc, 0, 0, 0);
        acc = __builtin_amdgcn_mfma_f32_16x16x32_bf16(Ah[ks], Wl, acc, 0, 0, 0);
      }
      float bv = bias[colt * 16 + lr];
      if (m == 0) {
#pragma unroll
        for (int r = 0; r < 4; ++r)
          phit[((size_t)b * NN + nD + r) * CC + colt * 16 + lr] = acc[r] + bv;
      } else {
        unsigned short* outp = (m == 1) ? psit : alpt;
#pragma unroll
        for (int r = 0; r < 4; ++r)
          outp[((size_t)b * NN + nD + r) * CC + colt * 16 + lr] = f2b(acc[r] + bv);
      }
    }
  }
}

// ================= down: out = dnW @ y + b + res  (y from pair planes) ==================
__global__ __launch_bounds__(256) void down_kernel(
    const unsigned short* __restrict__ yh, const unsigned short* __restrict__ yl,
    const unsigned short* __restrict__ wpk,
    const float* __restrict__ bias, const float* __restrict__ res,
    float* __restrict__ out)
{
  const int b = blockIdx.y, n0 = blockIdx.x * 64;
  const int tid = threadIdx.x, l = tid & 63, w = tid >> 6;
  const int lr = l & 15, lh = l >> 4;
  short8v Ah[2][4], Al[2][4];
#pragma unroll
  for (int ct = 0; ct < 2; ++ct)
#pragma unroll
    for (int ks = 0; ks < 4; ++ks) {
      Ah[ct][ks] = *(const short8v*)&wpk[((size_t)(((7 * 2 + 0) * 8 + (2 * w + ct)) * 4 + ks) * 64 + l) * 8];
      Al[ct][ks] = *(const short8v*)&wpk[((size_t)(((7 * 2 + 1) * 8 + (2 * w + ct)) * 4 + ks) * 64 + l) * 8];
    }
  f32x4 acc[2][4];
#pragma unroll
  for (int colt = 0; colt < 4; ++colt) {
    const int n = n0 + colt * 16 + lr;
    const unsigned short* yhp = yh + ((size_t)b * NN + n) * CC;
    const unsigned short* ylp = yl + ((size_t)b * NN + n) * CC;
#pragma unroll
    for (int ct = 0; ct < 2; ++ct) acc[ct][colt] = (f32x4){0.f, 0.f, 0.f, 0.f};
#pragma unroll
    for (int ks = 0; ks < 4; ++ks) {
      short8v Bh = *(const short8v*)&yhp[ks * 32 + lh * 8];
      short8v Bl = *(const short8v*)&ylp[ks * 32 + lh * 8];
#pragma unroll
      for (int ct = 0; ct < 2; ++ct) {
        acc[ct][colt] = __builtin_amdgcn_mfma_f32_16x16x32_bf16(Ah[ct][ks], Bh, acc[ct][colt], 0, 0, 0);
        acc[ct][colt] = __builtin_amdgcn_mfma_f32_16x16x32_bf16(Ah[ct][ks], Bl, acc[ct][colt], 0, 0, 0);
        acc[ct][colt] = __builtin_amdgcn_mfma_f32_16x16x32_bf16(Al[ct][ks], Bh, acc[ct][colt], 0, 0, 0);
      }
    }
  }
#pragma unroll
  for (int ct = 0; ct < 2; ++ct) {
    const int c0 = 32 * w + ct * 16 + lh * 4;
#pragma unroll
    for (int r = 0; r < 4; ++r) {
      float bv = bias[c0 + r];
#pragma unroll
      for (int colt = 0; colt < 4; ++colt) {
        size_t o = ((size_t)b * CC + c0 + r) * NN + n0 + colt * 16 + lr;
        out[o] = acc[ct][colt][r] + bv + res[o];
      }
    }
  }
}

// ================= Fused core: linear act (stride pre-rotates banks), bf16 psi gather ====
#define TNP 4
__global__ __launch_bounds__(256, 4) void fused_kernel(
    const float* __restrict__ p, const int* __restrict__ idxg,
    const float* __restrict__ phi_t, const unsigned short* __restrict__ psi_b,
    const unsigned short* __restrict__ alp_b, const unsigned short* __restrict__ wpk,
    const float* __restrict__ d1W, const float* __restrict__ d1b,
    const float* __restrict__ d2b, const float* __restrict__ g1b,
    const float* __restrict__ g2b,
    unsigned short* __restrict__ yh, unsigned short* __restrict__ yl)
{
  __shared__ __align__(16) unsigned short act[2][64][136];  // [hi/lo][col][c], 272B rows
  __shared__ int idxs[64];
  const int b = blockIdx.y;
  const int n0 = blockIdx.x * TNP;
  const int tid = threadIdx.x;
  const int l = tid & 63, w = tid >> 6;
  const int lr = l & 15, lh = l >> 4;

  if (tid < 64) idxs[tid] = idxg[((size_t)b * NN + n0 + (tid >> 4)) * KK + (tid & 15)];
  __syncthreads();

  // ---------- stage 0: rel -> pos1 = relu(d1W rel + d1b), hi/lo into act ----------
  {
    const int col = tid & 63, q = tid >> 6;
    const int pt = col >> 4;
    const int j = idxs[col];
    const float* pb = p + (size_t)b * 3 * NN;
    float r0 = pb[n0 + pt] - pb[j];
    float r1 = pb[NN + n0 + pt] - pb[NN + j];
    float r2 = pb[2 * NN + n0 + pt] - pb[2 * NN + j];
#pragma unroll
    for (int ch = 0; ch < 4; ++ch) {
      int c0 = q * 32 + ch * 8;
      float v[8];
#pragma unroll
      for (int e = 0; e < 8; ++e) {
        int c = c0 + e;
        v[e] = fmaxf(d1W[c * 3 + 0] * r0 + d1W[c * 3 + 1] * r1 + d1W[c * 3 + 2] * r2 + d1b[c], 0.f);
      }
      uint4 H, L;
      split2(v[0], v[1], H.x, L.x); split2(v[2], v[3], H.y, L.y);
      split2(v[4], v[5], H.z, L.z); split2(v[6], v[7], H.w, L.w);
      *(uint4*)&act[0][col][c0] = H;
      *(uint4*)&act[1][col][c0] = L;
    }
  }
  __syncthreads();

  int idxv[TNP];
#pragma unroll
  for (int colt = 0; colt < TNP; ++colt) idxv[colt] = idxs[colt * 16 + lr];

  f32x4 acc[2][TNP];
  short8v Af[2][4];

#define LOADA(MAT) do {                                                                 \
  _Pragma("unroll") for (int ct = 0; ct < 2; ++ct)                                      \
    _Pragma("unroll") for (int ks = 0; ks < 4; ++ks)                                    \
      Af[ct][ks] = *(const short8v*)&wpk[((size_t)((((MAT) * 2 + 0) * 8 + (2 * w + ct)) * 4 + ks) * 64 + l) * 8]; \
  } while (0)

#define MMUL() do {                                                                     \
  _Pragma("unroll") for (int ct = 0; ct < 2; ++ct)                                      \
    _Pragma("unroll") for (int colt = 0; colt < TNP; ++colt)                            \
      acc[ct][colt] = (f32x4){0.f, 0.f, 0.f, 0.f};                                      \
  _Pragma("unroll") for (int colt = 0; colt < TNP; ++colt) {                            \
    const int row_ = colt * 16 + lr;                                                    \
    short8v Bh[4], Bl[4];                                                               \
    _Pragma("unroll") for (int ks = 0; ks < 4; ++ks) {                                  \
      Bh[ks] = *(const short8v*)&act[0][row_][ks * 32 + lh * 8];                        \
      Bl[ks] = *(const short8v*)&act[1][row_][ks * 32 + lh * 8];                        \
    }                                                                                   \
    _Pragma("unroll") for (int ct = 0; ct < 2; ++ct)                                    \
      _Pragma("unroll") for (int ks = 0; ks < 4; ++ks) {                                \
        acc[ct][colt] = __builtin_amdgcn_mfma_f32_16x16x32_bf16(Af[ct][ks], Bh[ks],     \
                                                                acc[ct][colt], 0, 0, 0); \
        acc[ct][colt] = __builtin_amdgcn_mfma_f32_16x16x32_bf16(Af[ct][ks], Bl[ks],     \
                                                                acc[ct][colt], 0, 0, 0); \
      }                                                                                 \
  } } while (0)

  // ---------- d2: pos = d2W @ pos1 + d2b (kept in registers) ----------
  LOADA(0); MMUL();
  float pos[2][TNP][4];
#pragma unroll
  for (int ct = 0; ct < 2; ++ct) {
    f32x4 bv = *(const f32x4*)&d2b[32 * w + ct * 16 + lh * 4];
#pragma unroll
    for (int colt = 0; colt < TNP; ++colt)
#pragma unroll
      for (int r = 0; r < 4; ++r) pos[ct][colt][r] = acc[ct][colt][r] + bv[r];
  }
  __syncthreads();   // all waves done reading pos1

  // ---------- ain = pos + phi[n] - psi[idx] -> act (inline gathers; psi bf16) ----------
#pragma unroll
  for (int colt = 0; colt < TNP; ++colt) {
    size_t prow = ((size_t)b * NN + n0 + colt) * CC;
    size_t srow = ((size_t)b * NN + idxv[colt]) * CC;
#pragma unroll
    for (int ct = 0; ct < 2; ++ct) {
      int c0 = 32 * w + ct * 16 + lh * 4;
      f32x4 ph = *(const f32x4*)&phi_t[prow + c0];
      uint2 up = *(const uint2*)&psi_b[srow + c0];
      union { unsigned u; float f; } p0, p1, p2, p3;
      p0.u = up.x << 16; p1.u = up.x & 0xffff0000u;
      p2.u = up.y << 16; p3.u = up.y & 0xffff0000u;
      float psv[4] = {p0.f, p1.f, p2.f, p3.f};
      float v[4];
#pragma unroll
      for (int r = 0; r < 4; ++r) v[r] = pos[ct][colt][r] + ph[r] - psv[r];
      uint2 H, L;
      split2(v[0], v[1], H.x, L.x); split2(v[2], v[3], H.y, L.y);
      const int row = colt * 16 + lr;
      *(uint2*)&act[0][row][c0] = H;
      *(uint2*)&act[1][row][c0] = L;
    }
  }
  __syncthreads();

  // ---------- g1: h = relu(g1W @ ain + g1b) -> act ----------
  LOADA(1); MMUL();
  __syncthreads();   // all waves done reading ain
#pragma unroll
  for (int ct = 0; ct < 2; ++ct) {
    f32x4 bv = *(const f32x4*)&g1b[32 * w + ct * 16 + lh * 4];
    int c0 = 32 * w + ct * 16 + lh * 4;
#pragma unroll
    for (int colt = 0; colt < TNP; ++colt) {
      float v[4];
#pragma unroll
      for (int r = 0; r < 4; ++r) v[r] = fmaxf(acc[ct][colt][r] + bv[r], 0.f);
      uint2 H, L;
      split2(v[0], v[1], H.x, L.x); split2(v[2], v[3], H.y, L.y);
      const int row = colt * 16 + lr;
      *(uint2*)&act[0][row][c0] = H;
      *(uint2*)&act[1][row][c0] = L;
    }
  }
  __syncthreads();

  // ---------- g2: attn = g2W @ h + g2b ----------
  LOADA(2); MMUL();
#pragma unroll
  for (int ct = 0; ct < 2; ++ct) {
    f32x4 bv = *(const f32x4*)&g2b[32 * w + ct * 16 + lh * 4];
#pragma unroll
    for (int colt = 0; colt < TNP; ++colt)
#pragma unroll
      for (int r = 0; r < 4; ++r) acc[ct][colt][r] += bv[r];
  }

  // ---------- softmax over k (= lr lanes, group base broadcast; shift-invariant) ----------
#pragma unroll
  for (int ct = 0; ct < 2; ++ct)
#pragma unroll
    for (int colt = 0; colt < TNP; ++colt)
#pragma unroll
      for (int r = 0; r < 4; ++r) {
        float a = acc[ct][colt][r];
        float m = __shfl(a, l & 48);          // group-base value (exact softmax shift)
        float e = __expf(a - m);
        float s = e;
        s += __shfl_xor(s, 1);
        s += __shfl_xor(s, 2);
        s += __shfl_xor(s, 4);
        s += __shfl_xor(s, 8);
        acc[ct][colt][r] = e * __builtin_amdgcn_rcpf(s);
      }

  __syncthreads();   // all waves past their last act read (g2 MMUL) -> safe to reuse act
  unsigned short* yst = &act[0][0][0];   // staging: rows 0..3 = yh[colt], rows 4..7 = yl

  // ---------- combine: y_t[n][c] = sum_k wgt * (alpha[idx] + pos) ----------
#pragma unroll
  for (int colt = 0; colt < TNP; ++colt) {
    size_t arow = ((size_t)b * NN + idxv[colt]) * CC;
#pragma unroll
    for (int ct = 0; ct < 2; ++ct) {
      int c0 = 32 * w + ct * 16 + lh * 4;
      uint2 ua = *(const uint2*)&alp_b[arow + c0];
      union { unsigned u; float f; } a0, a1, a2, a3;
      a0.u = ua.x << 16; a1.u = ua.x & 0xffff0000u;
      a2.u = ua.y << 16; a3.u = ua.y & 0xffff0000u;
      float av[4] = {a0.f, a1.f, a2.f, a3.f};
      float yv[4];
#pragma unroll
      for (int r = 0; r < 4; ++r) {
        float part = acc[ct][colt][r] * (av[r] + pos[ct][colt][r]);
        part += __shfl_xor(part, 1);
        part += __shfl_xor(part, 2);
        part += __shfl_xor(part, 4);
        part += __shfl_xor(part, 8);
        yv[r] = part;
      }
      if (lr == 0) {
        uint2 H, L;
        split2(yv[0], yv[1], H.x, L.x); split2(yv[2], yv[3], H.y, L.y);
        *(uint2*)&yst[(size_t)colt * 128 + c0] = H;
        *(uint2*)&yst[(size_t)(4 + colt) * 128 + c0] = L;
      }
    }
  }
  __syncthreads();
  // ---------- coalesced y writeout: 2 KB, 16B per thread ----------
  if (tid < 128) {
    int plane = tid >> 6, row = (tid >> 4) & 3, chunk = tid & 15;
    uint4 v4 = *(const uint4*)&yst[(size_t)(plane * 4 + row) * 128 + chunk * 8];
    unsigned short* dst = (plane ? yl : yh) + ((size_t)b * NN + n0 + row) * CC + chunk * 8;
    *(uint4*)dst = v4;
  }
#undef LOADA
#undef MMUL
}

// =============================================================================================
extern "C" void kernel_launch(void* const* d_in, const int* in_sizes, int n_in,
                              void* d_out, int out_size, void* d_ws, size_t ws_size,
                              hipStream_t stream) {
  const float* input_p = (const float*)d_in[0];
  const float* input_x = (const float*)d_in[1];
  const float* top_W   = (const float*)d_in[2];  const float* top_b   = (const float*)d_in[3];
  const float* down_W  = (const float*)d_in[4];  const float* down_b  = (const float*)d_in[5];
  const float* phi_W   = (const float*)d_in[6];  const float* phi_b   = (const float*)d_in[7];
  const float* psi_W   = (const float*)d_in[8];  const float* psi_b   = (const float*)d_in[9];
  const float* alpha_W = (const float*)d_in[10]; const float* alpha_b = (const float*)d_in[11];
  const float* g1_W    = (const float*)d_in[12]; const float* g1_b    = (const float*)d_in[13];
  const float* g2_W    = (const float*)d_in[14]; const float* g2_b    = (const float*)d_in[15];
  const float* d1_W    = (const float*)d_in[16]; const float* d1_b    = (const float*)d_in[17];
  const float* d2_W    = (const float*)d_in[18]; const float* d2_b    = (const float*)d_in[19];
  float* out = (float*)d_out;

  char* ws = (char*)d_ws;
  int*            ws_idx   = (int*)ws;                                         // 1 MB
  unsigned short* ws_xin_h = (unsigned short*)(ws + (size_t)1  * (1 << 20));   // 4 MB (reused as y_h)
  unsigned short* ws_xin_l = (unsigned short*)(ws + (size_t)5  * (1 << 20));   // 4 MB (reused as y_l)
  float*          ws_phi   = (float*)(ws + (size_t)9  * (1 << 20));            // 8 MB (f32)
  unsigned short* ws_psi   = (unsigned short*)(ws + (size_t)17 * (1 << 20));   // 4 MB (bf16)
  unsigned short* ws_alp   = (unsigned short*)(ws + (size_t)21 * (1 << 20));   // 4 MB (bf16)
  float4*         ws_pkg   = (float4*)(ws + (size_t)25 * (1 << 20));           // 256 KB
  unsigned short* ws_wpk   = (unsigned short*)(ws + (size_t)25 * (1 << 20) + (1 << 18)); // 512 KB
  unsigned short* ws_y_h = ws_xin_h;   // xin consumed by feat; stream-ordered reuse
  unsigned short* ws_y_l = ws_xin_l;

  setup_kernel<<<640, 256, 0, stream>>>(input_p, input_x, d2_W, g1_W, g2_W, top_W,
                                        phi_W, psi_W, alpha_W, down_W,
                                        ws_pkg, ws_wpk, ws_xin_h, ws_xin_l);
  knn_kernel<<<dim3(NN / 64, BB), 512, 0, stream>>>(ws_pkg, ws_idx);
  feat_kernel<<<dim3(NN / 32, BB), 256, 0, stream>>>(ws_xin_h, ws_xin_l, ws_wpk,
                                                     top_b, phi_b, psi_b, alpha_b,
                                                     ws_phi, ws_psi, ws_alp);
  fused_kernel<<<dim3(NN / TNP, BB), 256, 0, stream>>>(input_p, ws_idx, ws_phi, ws_psi, ws_alp,
                                                       ws_wpk, d1_W, d1_b, d2_b, g1_b, g2_b,
                                                       ws_y_h, ws_y_l);
  down_kernel<<<dim3(NN / 64, BB), 256, 0, stream>>>(ws_y_h, ws_y_l, ws_wpk, down_b,
                                                     input_x, out);
}